// Round 5
// baseline (79.903 us; speedup 1.0000x reference)
//
#include <hip/hip_runtime.h>
#include <stdint.h>

// ---------------------------------------------------------------------------
// GSDepthRankingLoss on MI355X — R4: split kernels.
//   gs_bitpack : valid_mask -> 259KB bit table (L2-resident)
//   gs_sample  : PRNG + mask, per-block LDS compaction -> global worklist
//                (nbr baked into the 64-bit entry; 1 atomic per block)
//   gs_crop    : one 7x7 crop per thread, register-fenced batched row loads,
//                pair combine via shfl_xor(1), block reduce -> 3 atomics
// JAX threefry (partitionable) bit-exact (verified R0-R3, absmax 0).
// ---------------------------------------------------------------------------

#define IMG_W 1920
#define IMG_H 1080
#define N_PIX (IMG_W * IMG_H)
#define N_SAMP 518400         // int(1920*1080*0.25) == 2025 * 256
#define PAD_VAL (-1000000.0f)

typedef float f32x4 __attribute__((ext_vector_type(4)));

struct Keys { uint32_t k[5][2][2]; };  // [randint id][k1|k2][key word]

// Threefry-2x32, 20 rounds (Random123 / JAX-compatible).
static __host__ __device__ inline void tf2x32(uint32_t k0, uint32_t k1,
                                              uint32_t x0, uint32_t x1,
                                              uint32_t& o0, uint32_t& o1)
{
  const uint32_t ks2 = k0 ^ k1 ^ 0x1BD11BDAu;
  x0 += k0; x1 += k1;
#define TFR(r) { x0 += x1; x1 = (x1 << (r)) | (x1 >> (32 - (r))); x1 ^= x0; }
  TFR(13) TFR(15) TFR(26) TFR(6)
  x0 += k1;  x1 += ks2 + 1u;
  TFR(17) TFR(29) TFR(16) TFR(24)
  x0 += ks2; x1 += k0 + 2u;
  TFR(13) TFR(15) TFR(26) TFR(6)
  x0 += k0;  x1 += k1 + 3u;
  TFR(17) TFR(29) TFR(16) TFR(24)
  x0 += k1;  x1 += ks2 + 4u;
  TFR(13) TFR(15) TFR(26) TFR(6)
  x0 += ks2; x1 += k0 + 5u;
#undef TFR
  o0 = x0; o1 = x1;
}

__device__ __forceinline__ uint32_t jrbits(const uint32_t kk[2], uint32_t f)
{
  uint32_t a, b;
  tf2x32(kk[0], kk[1], 0u, f, a, b);   // partitionable: counts = (0, f)
  return a ^ b;                        // 32-bit fold
}

__device__ __forceinline__ uint32_t jrandint(const Keys& K, int r, uint32_t f,
                                             uint32_t span)
{
  const uint32_t hi = jrbits(K.k[r][0], f);
  const uint32_t lo = jrbits(K.k[r][1], f);
  uint32_t m = 65536u % span;
  m = (m * m) % span;
  return ((hi % span) * m + (lo % span)) % span;
}

static void compute_keys(Keys& K)
{
  uint32_t ks[5][2];
  for (uint32_t t = 0; t < 5; t++) {
    uint32_t a, b; tf2x32(0u, 42u, 0u, t, a, b);   // split of key(42)
    ks[t][0] = a; ks[t][1] = b;
  }
  for (int r = 0; r < 5; r++) {                    // randint's internal _split
    uint32_t a, b;
    tf2x32(ks[r][0], ks[r][1], 0u, 0u, a, b); K.k[r][0][0] = a; K.k[r][0][1] = b;
    tf2x32(ks[r][0], ks[r][1], 0u, 1u, a, b); K.k[r][1][0] = a; K.k[r][1][1] = b;
  }
}

__device__ __forceinline__ bool bittest(const unsigned long long* __restrict__ vb,
                                        uint32_t idx)
{
  return ((vb[idx >> 6] >> (idx & 63u)) & 1ull) != 0ull;
}

// ---------------- K1: bitpack valid mask (2073600 ints -> 259KB) ------------
__global__ __launch_bounds__(256) void gs_bitpack(
    const int* __restrict__ vmask,
    unsigned long long* __restrict__ vbits)
{
  const uint32_t gid = blockIdx.x * 256u + threadIdx.x;   // 8100*256 == N_PIX
  const unsigned long long ball = __ballot(vmask[gid] != 0);
  if ((threadIdx.x & 63u) == 0) vbits[gid >> 6] = ball;
}

// nbr-th nearest neighbour (by |depth-sd|, stable position ties) of the 7x7
// crop at (sy,sx). All 14 row-halves are pinned live via an asm register
// fence before the selection network runs -> single overlapped gather stall.
__device__ __forceinline__ int crop_neighbor(const float* __restrict__ tgt,
                                             int sy, int sx, float sd,
                                             uint32_t nbr)
{
  f32x4 A[7], B[7];
  const bool interior = (sy >= 3) && (sy <= IMG_H - 4) &&
                        (sx >= 3) && (sx <= IMG_W - 5);
  if (interior) {
    const float* p = tgt + (sy - 3) * IMG_W + (sx - 3);
#pragma unroll
    for (int r = 0; r < 7; r++) {
      __builtin_memcpy(&A[r], p + r * IMG_W,     16);
      __builtin_memcpy(&B[r], p + r * IMG_W + 4, 16);
    }
  } else {
    // rare edge path (~1e-4 of crops): guarded scalar loads, PAD semantics
#pragma unroll
    for (int r = 0; r < 7; r++) {
      const int yy = sy - 3 + r;
      const bool rok = (yy >= 0) && (yy < IMG_H);
#pragma unroll
      for (int c = 0; c < 8; c++) {
        const int xx = sx - 3 + c;
        const bool okc = rok && (c < 7) && (xx >= 0) && (xx < IMG_W);
        const float v = okc ? tgt[yy * IMG_W + xx] : PAD_VAL;
        if (c < 4) A[r][c] = v; else B[r][c - 4] = v;
      }
    }
  }
  // Register fence: all 56 floats must be materialized here (data dep pins
  // loads above; sched_barrier stops the sort being hoisted above the asm).
  asm volatile("" ::
      "v"(A[0]), "v"(A[1]), "v"(A[2]), "v"(A[3]), "v"(A[4]), "v"(A[5]), "v"(A[6]),
      "v"(B[0]), "v"(B[1]), "v"(B[2]), "v"(B[3]), "v"(B[4]), "v"(B[5]), "v"(B[6]));
  __builtin_amdgcn_sched_barrier(0);

  // 15 smallest of 49 unique keys: (|v-sd|bits & ~63) | pos. Stable ties ==
  // stable argsort. Pads rank >= 16 (>=16 in-bounds cells per crop).
  uint32_t arr[15];
#pragma unroll
  for (int t = 0; t < 15; t++) arr[t] = 0xFFFFFFFFu;

#pragma unroll
  for (int r = 0; r < 7; r++) {
    const float vals[8] = { A[r][0], A[r][1], A[r][2], A[r][3],
                            B[r][0], B[r][1], B[r][2], B[r][3] };
#pragma unroll
    for (int c = 0; c < 7; c++) {
      const int q = r * 7 + c;
      uint32_t key = (__float_as_uint(vals[c] - sd) & 0x7FFFFFC0u) | (uint32_t)q;
      const int depth = (q + 1 < 15) ? (q + 1) : 15;   // triangular insert
#pragma unroll
      for (int t = 0; t < 15; t++) {
        if (t < depth) {
          const uint32_t lo = min(key, arr[t]);
          const uint32_t hi = max(key, arr[t]);
          arr[t] = lo; key = hi;
        }
      }
    }
  }

  uint32_t relkey = 0;
#pragma unroll
  for (int t = 1; t < 15; t++)
    if ((uint32_t)t == nbr) relkey = arr[t];
  const uint32_t rel = relkey & 63u;
  return (sy - 3 + (int)(rel / 7u)) * IMG_W + (sx - 3 + (int)(rel % 7u));
}

// ---------------- K2: PRNG + mask -> compacted global worklist --------------
// Entry (64b): [nbr1:4 @48][nbr0:4 @44][sy0:11 @33][sx0:11 @22][sy1:11 @11][sx1:11 @0]
__global__ __launch_bounds__(256) void gs_sample(
    const unsigned long long* __restrict__ vbits,
    uint32_t* __restrict__ wcount,
    unsigned long long* __restrict__ wlist,
    Keys K)
{
  __shared__ unsigned long long ent[256];
  __shared__ uint32_t scnt[4];
  __shared__ uint32_t gbase_s;

  const uint32_t tid  = threadIdx.x;
  const uint32_t lane = tid & 63u;
  const uint32_t wave = tid >> 6;
  const uint32_t ui   = blockIdx.x * 256u + tid;   // grid covers N_SAMP exactly

  const uint32_t syb = jrandint(K, 0, ui, 840u);    // H - 240
  const uint32_t sxb = jrandint(K, 1, ui, 1680u);   // W - 240
  const uint32_t sy0 = syb + jrandint(K, 2, 2u * ui,      240u);
  const uint32_t sy1 = syb + jrandint(K, 2, 2u * ui + 1u, 240u);
  const uint32_t sx0 = sxb + jrandint(K, 3, 2u * ui,      240u);
  const uint32_t sx1 = sxb + jrandint(K, 3, 2u * ui + 1u, 240u);
  const bool ok = bittest(vbits, sy0 * IMG_W + sx0) &&
                  bittest(vbits, sy1 * IMG_W + sx1);

  const unsigned long long ball = __ballot(ok);
  if (lane == 0) scnt[wave] = (uint32_t)__popcll(ball);
  __syncthreads();

  uint32_t base = 0;
#pragma unroll
  for (uint32_t w = 0; w < 4; w++) if (w < wave) base += scnt[w];
  const uint32_t nsurv = scnt[0] + scnt[1] + scnt[2] + scnt[3];

  if (ok) {
    const uint32_t nbr0 = 1u + jrandint(K, 4, 2u * ui,      14u);  // [1,15)
    const uint32_t nbr1 = 1u + jrandint(K, 4, 2u * ui + 1u, 14u);
    const uint32_t pos = base + (uint32_t)__popcll(ball & ((1ull << lane) - 1ull));
    ent[pos] = ((unsigned long long)nbr1 << 48) | ((unsigned long long)nbr0 << 44) |
               ((unsigned long long)sy0  << 33) | ((unsigned long long)sx0  << 22) |
               ((unsigned long long)sy1  << 11) |  (unsigned long long)sx1;
  }
  if (tid == 0 && nsurv) gbase_s = atomicAdd(wcount, nsurv);
  __syncthreads();

  const uint32_t gbase = gbase_s;
  for (uint32_t t = tid; t < nsurv; t += 256u)
    wlist[gbase + t] = ent[t];          // coalesced
}

// ---------------- K3: one crop per thread, pair-combine via shfl ------------
__global__ __launch_bounds__(256, 4) void gs_crop(
    const float* __restrict__ tgt,
    const float* __restrict__ rnd,
    const unsigned long long* __restrict__ vbits,
    const uint32_t* __restrict__ wcount,
    const unsigned long long* __restrict__ wlist,
    float* __restrict__ acc)
{
  const uint32_t n2 = 2u * *wcount;                 // crops
  if (blockIdx.x * 256u >= n2) return;              // uniform early block exit

  __shared__ float partial[12];
  const uint32_t tid  = threadIdx.x;
  const uint32_t lane = tid & 63u;
  const uint32_t wave = tid >> 6;
  const uint32_t t = blockIdx.x * 256u + tid;

  float sd = 0.f, r = 0.f, q = 0.f;
  bool v = false;
  if (t < n2) {                                     // pair lanes share fate
    const unsigned long long e = wlist[t >> 1];
    const int j = (int)(t & 1u);
    const int sy  = j ? (int)((e >> 11) & 2047u) : (int)((e >> 33) & 2047u);
    const int sx  = j ? (int)( e        & 2047u) : (int)((e >> 22) & 2047u);
    const uint32_t nbr = j ? (uint32_t)((e >> 48) & 15u)
                           : (uint32_t)((e >> 44) & 15u);
    const int sidx = sy * IMG_W + sx;
    sd = tgt[sidx];
    r  = rnd[sidx];
    const int nidx = crop_neighbor(tgt, sy, sx, sd, nbr);
    v = bittest(vbits, (uint32_t)nidx);
    q = rnd[nidx];
  }

  // partner exchange (lanes 2k <-> 2k+1, always same wave; n2 is even)
  const float psd = __shfl_xor(sd, 1);
  const float pr  = __shfl_xor(r, 1);
  const bool  pv  = (bool)__shfl_xor((int)v, 1);
  const bool pairok = (t < n2) && v && pv;

  float cont_c = pairok ? fmaxf(fabsf(r - q) - 1e-4f, 0.f) : 0.f;
  float rank_c = 0.f, cnt_c = 0.f;
  if (pairok && ((t & 1u) == 0)) {                  // even lane owns the pair
    const bool keep = sd >= psd;                    // stable argsort(-depth)
    const float ra = keep ? r : pr;
    const float rb = keep ? pr : r;
    rank_c = fmaxf(ra - rb + 1e-4f, 0.f);
    cnt_c = 1.f;
  }

  // wave reduce -> LDS -> 3 atomics per block
#pragma unroll
  for (int off = 32; off > 0; off >>= 1) {
    rank_c += __shfl_down(rank_c, off);
    cont_c += __shfl_down(cont_c, off);
    cnt_c  += __shfl_down(cnt_c, off);
  }
  if (lane == 0) {
    partial[wave * 3 + 0] = rank_c;
    partial[wave * 3 + 1] = cont_c;
    partial[wave * 3 + 2] = cnt_c;
  }
  __syncthreads();
  if (tid < 3) {
    const float s = partial[tid] + partial[3 + tid] +
                    partial[6 + tid] + partial[9 + tid];
    atomicAdd(acc + tid, s);
  }
}

// ---------------- fallback (ws too small): R3 fused, raw vmask --------------
__global__ __launch_bounds__(256, 2) void gs_fused(
    const float* __restrict__ tgt,
    const float* __restrict__ rnd,
    const int*   __restrict__ vmask,
    float* __restrict__ acc,
    Keys K)
{
  __shared__ float partial[12];
  const uint32_t tid  = threadIdx.x;
  const uint32_t lane = tid & 63u;
  const uint32_t wave = tid >> 6;
  const uint32_t ui   = blockIdx.x * 256u + tid;

  float rank_c = 0.f, cont_c = 0.f, cnt_c = 0.f;
  if (ui < N_SAMP) {
    const uint32_t syb = jrandint(K, 0, ui, 840u);
    const uint32_t sxb = jrandint(K, 1, ui, 1680u);
    int sy[2], sx[2], sidx[2];
    float sd[2];
    bool sm = true;
#pragma unroll
    for (int j = 0; j < 2; j++) {
      sy[j] = (int)(syb + jrandint(K, 2, 2u * ui + (uint32_t)j, 240u));
      sx[j] = (int)(sxb + jrandint(K, 3, 2u * ui + (uint32_t)j, 240u));
      sidx[j] = sy[j] * IMG_W + sx[j];
      sd[j] = tgt[sidx[j]];
      sm = sm && (vmask[sidx[j]] != 0);
    }
    if (sm) {
      int nidx[2]; bool nm = true;
#pragma unroll
      for (int j = 0; j < 2; j++) {
        const uint32_t nbr = 1u + jrandint(K, 4, 2u * ui + (uint32_t)j, 14u);
        nidx[j] = crop_neighbor(tgt, sy[j], sx[j], sd[j], nbr);
        nm = nm && (vmask[nidx[j]] != 0);
      }
      if (nm) {
        const float r0 = rnd[sidx[0]], r1 = rnd[sidx[1]];
        const float q0 = rnd[nidx[0]], q1 = rnd[nidx[1]];
        const bool keep = sd[0] >= sd[1];
        const float ra = keep ? r0 : r1;
        const float rb = keep ? r1 : r0;
        rank_c = fmaxf(ra - rb + 1e-4f, 0.f);
        cont_c = fmaxf(fabsf(r0 - q0) - 1e-4f, 0.f)
               + fmaxf(fabsf(r1 - q1) - 1e-4f, 0.f);
        cnt_c = 1.f;
      }
    }
  }
#pragma unroll
  for (int off = 32; off > 0; off >>= 1) {
    rank_c += __shfl_down(rank_c, off);
    cont_c += __shfl_down(cont_c, off);
    cnt_c  += __shfl_down(cnt_c, off);
  }
  if (lane == 0) {
    partial[wave * 3 + 0] = rank_c;
    partial[wave * 3 + 1] = cont_c;
    partial[wave * 3 + 2] = cnt_c;
  }
  __syncthreads();
  if (tid < 3) {
    const float s = partial[tid] + partial[3 + tid] +
                    partial[6 + tid] + partial[9 + tid];
    atomicAdd(acc + tid, s);
  }
}

__global__ void gs_finalize(const float* __restrict__ acc, float* __restrict__ out)
{
  const float denom = fmaxf(acc[2], 1.0f);
  out[0] = 0.2f * (acc[0] / denom);                 // WEIGHT * rank_mean
  out[1] = 0.2f * 0.1f * (acc[1] / (denom * 2.0f)); // WEIGHT*CONT_W * cont_mean
}

extern "C" void kernel_launch(void* const* d_in, const int* in_sizes, int n_in,
                              void* d_out, int out_size, void* d_ws, size_t ws_size,
                              hipStream_t stream)
{
  (void)in_sizes; (void)n_in; (void)out_size;
  const float* tgt   = (const float*)d_in[0];
  const float* rnd   = (const float*)d_in[1];
  const int*   vmask = (const int*)d_in[2];
  float* out = (float*)d_out;

  // ws layout: [acc 3f + wcount u32 = 16B][vbits 259200B][wlist N_SAMP*8B]
  float*    acc    = (float*)d_ws;
  uint32_t* wcount = (uint32_t*)d_ws + 3;
  unsigned long long* vbits = (unsigned long long*)((char*)d_ws + 16);
  unsigned long long* wlist =
      (unsigned long long*)((char*)d_ws + 16 + (size_t)(N_PIX / 64) * 8);
  const size_t need = 16 + (size_t)(N_PIX / 64) * 8 + (size_t)N_SAMP * 8;

  Keys K;
  compute_keys(K);

  hipMemsetAsync(d_ws, 0, 16, stream);

  if (ws_size >= need) {
    gs_bitpack<<<N_PIX / 256, 256, 0, stream>>>(vmask, vbits);
    gs_sample<<<N_SAMP / 256, 256, 0, stream>>>(vbits, wcount, wlist, K);
    gs_crop<<<(2 * N_SAMP + 255) / 256, 256, 0, stream>>>(
        tgt, rnd, vbits, wcount, wlist, acc);
  } else {
    gs_fused<<<N_SAMP / 256, 256, 0, stream>>>(tgt, rnd, vmask, acc, K);
  }
  gs_finalize<<<1, 1, 0, stream>>>(acc, out);
}